// Round 11
// baseline (187.482 us; speedup 1.0000x reference)
//
#include <hip/hip_runtime.h>
#include <hip/hip_bf16.h>

#define EPSF 1e-5f

typedef __attribute__((ext_vector_type(8))) short bf16x8;
typedef __attribute__((ext_vector_type(4))) float f32x4;
typedef __attribute__((ext_vector_type(2))) unsigned int u32x2;
typedef __attribute__((ext_vector_type(4))) unsigned int u32x4;

constexpr int B_ = 2, N_ = 16384;
constexpr int HSTR = 72;   // hbuf row stride (bf16 elems)
constexpr int RSTR = 72;
constexpr int PPW  = 4;    // points per wave
constexpr int PPB  = 16;   // points per block
constexpr size_t PP_BYTES = (size_t)B_ * N_ * 16;   // 512 KiB padded points

__device__ __forceinline__ short f2bf(float f) {
    __hip_bfloat16 h = __float2bfloat16(f);
    short s; __builtin_memcpy(&s, &h, 2); return s;
}
__device__ __forceinline__ unsigned int pkbf(float a, float b) {
    float2 f2; f2.x = a; f2.y = b;
    __hip_bfloat162 h = __float22bfloat162_rn(f2);
    unsigned int u; __builtin_memcpy(&u, &h, 4); return u;
}
__device__ __forceinline__ f32x4 splat4(float v) { f32x4 r = {v, v, v, v}; return r; }

// prep: points -> padded float4
__global__ __launch_bounds__(256) void prep_points(
    const float* __restrict__ pts, float* __restrict__ pp)
{
    const int i = blockIdx.x * 256 + threadIdx.x;
    if (i < B_ * N_) {
        f32x4 o = { pts[3 * i], pts[3 * i + 1], pts[3 * i + 2], 0.f };
        ((f32x4*)pp)[i] = o;
    }
}

// R6 base + MFMA1 operand swap: A=Wpos (m=channel), B=geo (n=neighbor).
// D[m=c][n=k]: lane's C-frag reg r spans 4 consecutive channels for its OWN
// neighbor giv[nt] -> feature gather uses lane-local index (no shfl broadcast),
// ep1 is layout-aligned f32x4 vector math, bias rides the MFMA C-operand.
// GCM / ep2 / phase D identical to R6 (d-interleave l15*4+nt, wb2+wb3 in LDS).
template<bool PAD>
__global__ __launch_bounds__(256) void bridgenet11(
    const float* __restrict__ points,
    const float* __restrict__ pp,
    const float* __restrict__ features,
    const int*   __restrict__ gidx,
    const float* __restrict__ Wpos,
    const float* __restrict__ bposv,
    const float* __restrict__ bn1g, const float* __restrict__ bn1b,
    const float* __restrict__ bn1m, const float* __restrict__ bn1v,
    const float* __restrict__ Wgcm,
    const float* __restrict__ bgcm,
    const float* __restrict__ bn2g, const float* __restrict__ bn2b,
    const float* __restrict__ bn2m, const float* __restrict__ bn2v,
    const float* __restrict__ Watt,
    const float* __restrict__ batt,
    const float* __restrict__ Wout,
    const float* __restrict__ bout,
    const float* __restrict__ lng, const float* __restrict__ lnb,
    float* __restrict__ out)
{
    __shared__ __align__(16) short hbuf[4][32 * HSTR];
    __shared__ __align__(16) short resstage[PPB * RSTR];
    __shared__ __align__(16) short wb2[8 * 64 * 8];   // GCM B-frags (ps2-folded)
    __shared__ __align__(16) short wb3[8 * 64 * 8];   // out B-frags

    const int t    = threadIdx.x;
    const int w    = t >> 6;
    const int l    = t & 63;
    const int l15  = l & 15;
    const int quad = l >> 4;
    const int c4   = l15 * 4;     // GCM-output channel base (interleaved map)
    const int cq   = quad * 4;    // MFMA1-output channel sub-base

    // ---- wave 0 stages GCM (ps2-folded) + out weight fragments into LDS ----
    if (w == 0) {
        #pragma unroll
        for (int nt = 0; nt < 4; ++nt) {
            const int d = c4 + nt;
            const float ps2d = bn2g[d] * rsqrtf(bn2v[d] + EPSF);
            #pragma unroll
            for (int ks = 0; ks < 2; ++ks) {
                bf16x8 f2, f3;
                #pragma unroll
                for (int j = 0; j < 8; ++j) {
                    f2[j] = f2bf(ps2d * Wgcm[d * 64 + ks * 32 + quad * 8 + j]);
                    f3[j] = f2bf(Wout[d * 64 + ks * 32 + quad * 8 + j]);
                }
                *(bf16x8*)&wb2[((nt * 2 + ks) * 64 + l) * 8] = f2;
                *(bf16x8*)&wb3[((nt * 2 + ks) * 64 + l) * 8] = f3;
            }
        }
    }

    // ---- per-wave constant state ----
    // MFMA1 A-frags: A[m = mt*16 + l15][g = quad*8+j] = ps1(c)*Wpos[c][g]
    bf16x8 bposfA[4];
    #pragma unroll
    for (int mt = 0; mt < 4; ++mt) {
        const int c = mt * 16 + l15;
        const float ps1c = bn1g[c] * rsqrtf(bn1v[c] + EPSF);
        #pragma unroll
        for (int j = 0; j < 8; ++j) {
            const int g = quad * 8 + j;
            bposfA[mt][j] = f2bf(g < 10 ? ps1c * Wpos[c * 10 + g] : 0.f);
        }
    }
    // MFMA1 C-operand bias: channels mt*16 + cq + r  (vector loads)
    f32x4 pbc1A[4];
    #pragma unroll
    for (int mt = 0; mt < 4; ++mt) {
        const int cb = mt * 16 + cq;
        const f32x4 g1 = *(const f32x4*)(bn1g + cb);
        const f32x4 b1 = *(const f32x4*)(bn1b + cb);
        const f32x4 m1 = *(const f32x4*)(bn1m + cb);
        const f32x4 v1 = *(const f32x4*)(bn1v + cb);
        const f32x4 bp = *(const f32x4*)(bposv + cb);
        #pragma unroll
        for (int r = 0; r < 4; ++r) {
            const float ps1 = g1[r] * rsqrtf(v1[r] + EPSF);
            pbc1A[mt][r] = ps1 * (bp[r] - m1[r]) + b1[r];
        }
    }
    // GCM bias splats (d = c4 + nt, interleaved)
    f32x4 pbc2[4];
    {
        const f32x4 g2 = *(const f32x4*)(bn2g + c4);
        const f32x4 b2 = *(const f32x4*)(bn2b + c4);
        const f32x4 m2 = *(const f32x4*)(bn2m + c4);
        const f32x4 v2 = *(const f32x4*)(bn2v + c4);
        const f32x4 bg = *(const f32x4*)(bgcm + c4);
        #pragma unroll
        for (int nt = 0; nt < 4; ++nt) {
            const float ps2 = g2[nt] * rsqrtf(v2[nt] + EPSF);
            pbc2[nt] = splat4(ps2 * (bg[nt] - m2[nt]) + b2[nt]);
        }
    }
    float wat[2][4];
    #pragma unroll
    for (int mt = 0; mt < 2; ++mt)
        #pragma unroll
        for (int r = 0; r < 4; ++r)
            wat[mt][r] = Watt[mt * 16 + quad * 4 + r];
    const float battv = batt[0];

    const f32x4 zero4 = {0.f, 0.f, 0.f, 0.f};
    short* hb = hbuf[w];
    const int base = blockIdx.x * PPB + w * PPW;
    const int bb   = (base >> 14) * N_;

    __syncthreads();   // weight LDS ready

    for (int i = 0; i < PPW; ++i) {
        const int pt = base + i;

        // --- loads: lane-local neighbor index giv[nt] feeds coords AND features ---
        int giv[2];
        giv[0] = gidx[(size_t)pt * 32 + l15];
        giv[1] = gidx[(size_t)pt * 32 + 16 + l15];
        const f32x4 resid = *(const f32x4*)(features + (size_t)pt * 64 + c4);
        float xi0, xi1, xi2;
        float px[2], py[2], pz[2];
        if (PAD) {
            const f32x4 x4 = *(const f32x4*)(pp + (size_t)pt * 4);
            xi0 = x4[0]; xi1 = x4[1]; xi2 = x4[2];
            #pragma unroll
            for (int nt = 0; nt < 2; ++nt) {
                const f32x4 p4 = *(const f32x4*)(pp + (size_t)(bb + giv[nt]) * 4);
                px[nt] = p4[0]; py[nt] = p4[1]; pz[nt] = p4[2];
            }
        } else {
            xi0 = points[(size_t)pt * 3];
            xi1 = points[(size_t)pt * 3 + 1];
            xi2 = points[(size_t)pt * 3 + 2];
            #pragma unroll
            for (int nt = 0; nt < 2; ++nt) {
                const float* ppt = points + (size_t)(bb + giv[nt]) * 3;
                px[nt] = ppt[0]; py[nt] = ppt[1]; pz[nt] = ppt[2];
            }
        }
        // feature rows of lane's own neighbors, channel chunks mt*16+cq
        f32x4 f4[4][2];
        #pragma unroll
        for (int nt = 0; nt < 2; ++nt) {
            const float* frow = features + (size_t)(bb + giv[nt]) * 64 + cq;
            #pragma unroll
            for (int mt = 0; mt < 4; ++mt)
                f4[mt][nt] = *(const f32x4*)(frow + mt * 16);
        }

        // --- geo B-frags (n = nt*16 + l15, k = quad*8+j) ---
        bf16x8 ageo[2];
        #pragma unroll
        for (int nt = 0; nt < 2; ++nt) {
            const float dx = xi0 - px[nt], dy = xi1 - py[nt], dz = xi2 - pz[nt];
            const float dist = sqrtf(dx * dx + dy * dy + dz * dz);
            u32x4 u = {0u, 0u, 0u, 0u};
            if (quad == 0) {
                u[0] = pkbf(xi0, xi1); u[1] = pkbf(xi2, px[nt]);
                u[2] = pkbf(py[nt], pz[nt]); u[3] = pkbf(dx, dy);
            } else if (quad == 1) {
                u[0] = pkbf(dz, dist);
            }
            __builtin_memcpy(&ageo[nt], &u, 16);
        }

        // --- pos-MLP MFMA, swapped: D[m=c][n=k] = Wpos^T-frag x geo + bias ---
        f32x4 acc1[4][2];
        #pragma unroll
        for (int mt = 0; mt < 4; ++mt)
            #pragma unroll
            for (int nt = 0; nt < 2; ++nt)
                acc1[mt][nt] = __builtin_amdgcn_mfma_f32_16x16x32_bf16(
                    bposfA[mt], ageo[nt], pbc1A[mt], 0, 0, 0);

        // --- epilogue 1: layout-aligned vector relu+add, b64 writes ---
        #pragma unroll
        for (int nt = 0; nt < 2; ++nt)
            #pragma unroll
            for (int mt = 0; mt < 4; ++mt) {
                const f32x4 v = f4[mt][nt] + __builtin_elementwise_max(acc1[mt][nt], zero4);
                u32x2 hv = { pkbf(v[0], v[1]), pkbf(v[2], v[3]) };
                *(u32x2*)&hb[(nt * 16 + l15) * HSTR + mt * 16 + cq] = hv;
            }

        // --- GCM: A-frags from LDS, B-frags from LDS (ps2-folded), bias in C ---
        bf16x8 a2[2][2];
        #pragma unroll
        for (int mt = 0; mt < 2; ++mt)
            #pragma unroll
            for (int ks = 0; ks < 2; ++ks)
                a2[mt][ks] = *(const bf16x8*)&hb[(mt * 16 + l15) * HSTR + ks * 32 + quad * 8];
        f32x4 acc2[2][4];
        #pragma unroll
        for (int nt = 0; nt < 4; ++nt) {
            const bf16x8 b0 = *(const bf16x8*)&wb2[((nt * 2 + 0) * 64 + l) * 8];
            const bf16x8 b1 = *(const bf16x8*)&wb2[((nt * 2 + 1) * 64 + l) * 8];
            #pragma unroll
            for (int mt = 0; mt < 2; ++mt) {
                f32x4 a = __builtin_amdgcn_mfma_f32_16x16x32_bf16(a2[mt][0], b0, pbc2[nt], 0, 0, 0);
                acc2[mt][nt] = __builtin_amdgcn_mfma_f32_16x16x32_bf16(a2[mt][1], b1, a, 0, 0, 0);
            }
        }

        // --- epilogue 2: relu + attention softmax (shift-invariant) + pool ---
        float res[4];
        {
            float sp[4], mk[4];
            #pragma unroll
            for (int nt = 0; nt < 4; ++nt) {
                sp[nt] = 0.f; mk[nt] = 0.f;
                #pragma unroll
                for (int mt = 0; mt < 2; ++mt)
                    #pragma unroll
                    for (int r = 0; r < 4; ++r) {
                        const float h2 = fmaxf(acc2[mt][nt][r], 0.f);
                        sp[nt] += h2 * wat[mt][r];
                        mk[nt] = fmaxf(mk[nt], h2);
                    }
                sp[nt] += __shfl_xor(sp[nt], 16);
                sp[nt] += __shfl_xor(sp[nt], 32);
                mk[nt] = fmaxf(mk[nt], __shfl_xor(mk[nt], 16));
                mk[nt] = fmaxf(mk[nt], __shfl_xor(mk[nt], 32));
            }
            float e[4], s = 0.f;
            #pragma unroll
            for (int nt = 0; nt < 4; ++nt) { e[nt] = __expf(sp[nt] + battv); s += e[nt]; }
            #pragma unroll
            for (int o = 1; o < 16; o <<= 1) s += __shfl_xor(s, o);
            const float inv = 1.f / s;
            #pragma unroll
            for (int nt = 0; nt < 4; ++nt)
                res[nt] = e[nt] * inv * mk[nt] + resid[nt];
        }
        if (quad == 0) {
            u32x2 rv = { pkbf(res[0], res[1]), pkbf(res[2], res[3]) };
            *(u32x2*)&resstage[(w * PPW + i) * RSTR + c4] = rv;
        }
    }

    __syncthreads();

    // ---------- phase D: batched out-matmul + LayerNorm + relu ----------
    const f32x4 lngv  = *(const f32x4*)(lng + c4);
    const f32x4 lnbv  = *(const f32x4*)(lnb + c4);
    const f32x4 boutv = *(const f32x4*)(bout + c4);
    bf16x8 a3[2];
    #pragma unroll
    for (int ks = 0; ks < 2; ++ks)
        a3[ks] = *(const bf16x8*)&resstage[l15 * RSTR + ks * 32 + quad * 8];
    f32x4 acc3[4];
    #pragma unroll
    for (int nt = 0; nt < 4; ++nt) {
        const bf16x8 b0 = *(const bf16x8*)&wb3[((nt * 2 + 0) * 64 + l) * 8];
        const bf16x8 b1 = *(const bf16x8*)&wb3[((nt * 2 + 1) * 64 + l) * 8];
        f32x4 a = __builtin_amdgcn_mfma_f32_16x16x32_bf16(a3[0], b0, zero4, 0, 0, 0);
        acc3[nt] = __builtin_amdgcn_mfma_f32_16x16x32_bf16(a3[1], b1, a, 0, 0, 0);
    }
    float y[4], s = 0.f;
    #pragma unroll
    for (int nt = 0; nt < 4; ++nt) { y[nt] = acc3[nt][w] + boutv[nt]; s += y[nt]; }
    #pragma unroll
    for (int o = 1; o < 16; o <<= 1) s += __shfl_xor(s, o);
    const float mu = s * (1.f / 64.f);
    float dv[4], v2 = 0.f;
    #pragma unroll
    for (int nt = 0; nt < 4; ++nt) { dv[nt] = y[nt] - mu; v2 += dv[nt] * dv[nt]; }
    #pragma unroll
    for (int o = 1; o < 16; o <<= 1) v2 += __shfl_xor(v2, o);
    const float rs = rsqrtf(v2 * (1.f / 64.f) + EPSF);
    const int pto = blockIdx.x * PPB + quad * 4 + w;
    f32x4 ov;
    #pragma unroll
    for (int nt = 0; nt < 4; ++nt)
        ov[nt] = fmaxf(lngv[nt] * dv[nt] * rs + lnbv[nt], 0.f);
    *(f32x4*)(out + (size_t)pto * 64 + c4) = ov;
}

extern "C" void kernel_launch(void* const* d_in, const int* in_sizes, int n_in,
                              void* d_out, int out_size, void* d_ws, size_t ws_size,
                              hipStream_t stream) {
    const float* points   = (const float*)d_in[0];
    const float* features = (const float*)d_in[1];
    const int*   gidxp    = (const int*)d_in[2];
    const bool   pad      = (ws_size >= PP_BYTES);
    float* pp = (float*)d_ws;
    if (pad) {
        hipLaunchKernelGGL(prep_points, dim3((B_ * N_ + 255) / 256), dim3(256), 0, stream,
                           points, pp);
        hipLaunchKernelGGL((bridgenet11<true>), dim3((B_ * N_) / PPB), dim3(256), 0, stream,
            points, pp, features, gidxp,
            (const float*)d_in[3],  (const float*)d_in[4],
            (const float*)d_in[5],  (const float*)d_in[6],  (const float*)d_in[7],  (const float*)d_in[8],
            (const float*)d_in[9],  (const float*)d_in[10],
            (const float*)d_in[11], (const float*)d_in[12], (const float*)d_in[13], (const float*)d_in[14],
            (const float*)d_in[15], (const float*)d_in[16],
            (const float*)d_in[17], (const float*)d_in[18],
            (const float*)d_in[19], (const float*)d_in[20],
            (float*)d_out);
    } else {
        hipLaunchKernelGGL((bridgenet11<false>), dim3((B_ * N_) / PPB), dim3(256), 0, stream,
            points, pp, features, gidxp,
            (const float*)d_in[3],  (const float*)d_in[4],
            (const float*)d_in[5],  (const float*)d_in[6],  (const float*)d_in[7],  (const float*)d_in[8],
            (const float*)d_in[9],  (const float*)d_in[10],
            (const float*)d_in[11], (const float*)d_in[12], (const float*)d_in[13], (const float*)d_in[14],
            (const float*)d_in[15], (const float*)d_in[16],
            (const float*)d_in[17], (const float*)d_in[18],
            (const float*)d_in[19], (const float*)d_in[20],
            (float*)d_out);
    }
}